// Round 2
// baseline (583.509 us; speedup 1.0000x reference)
//
#include <hip/hip_runtime.h>

#define NEGV -10000.0f
#define BB 1024
#define TT 512
#define KK 64

typedef float vf2 __attribute__((ext_vector_type(2)));

// ---------------------------------------------------------------------------
// K0: trans = log_softmax(A + inv_mask*NEG, axis=-1); also store transpose.
// ---------------------------------------------------------------------------
__global__ __launch_bounds__(64)
void trans_kernel(const float* __restrict__ A, const int* __restrict__ inv,
                  float* __restrict__ trans, float* __restrict__ transT)
{
    const int i = blockIdx.x, j = threadIdx.x;
    float x = A[i * KK + j] + (inv[i * KK + j] ? NEGV : 0.0f);
    float m = x;
    #pragma unroll
    for (int o = 32; o > 0; o >>= 1) m = fmaxf(m, __shfl_xor(m, o));
    float e = expf(x - m);
    float s = e;
    #pragma unroll
    for (int o = 32; o > 0; o >>= 1) s += __shfl_xor(s, o);
    float t = (x - m) - logf(s);
    trans[i * KK + j]  = t;
    transT[j * KK + i] = t;
}

// ---------------------------------------------------------------------------
// K1: fused Viterbi forward + backtrack. One wave per batch row; lane = tag.
// Deep (depth-8) ring-buffer prefetch of global rows hides ~900-cyc HBM
// latency under the ~250-cyc/step compute chain (R1 post-mortem: depth-1
// prefetch made every step pay full HBM latency -> 960 cyc/step).
// alpha history overwrites consumed unary rows in place; backward recomputes
// the surviving-path argmax with bitwise-identical adds (ballot+ffs = first-
// index argmax, matching jnp.argmax ties; validated absmax=0 in R1).
// ---------------------------------------------------------------------------
__global__ __launch_bounds__(64)
void viterbi_kernel(float* __restrict__ unary, const int* __restrict__ lengths,
                    const float* __restrict__ trans, const float* __restrict__ transT,
                    int* __restrict__ out)
{
    const int lane = threadIdx.x;
    const int b = blockIdx.x;

    __shared__ float  sT[KK * KK];   // sT[tag*64 + i] — row-contiguous, conflict-free
    __shared__ float4 sA4[2][16];    // alpha broadcast (double-buffered)

    #pragma unroll 4
    for (int r = 0; r < KK; ++r) sT[r * KK + lane] = transT[r * KK + lane];

    // Treg2[i] = {trans[2i][lane], trans[2i+1][lane]} — vf2 to coax v_pk_add_f32
    vf2 Treg2[KK / 2];
    #pragma unroll
    for (int i = 0; i < KK / 2; ++i) {
        Treg2[i].x = trans[(2 * i)     * KK + lane];
        Treg2[i].y = trans[(2 * i + 1) * KK + lane];
    }

    const int len = lengths[b];                      // 1..512, wave-uniform
    float* urow = unary + (long)b * (TT * KK);
    int*   orow = out + b * TT;

    // depth-8 unary prefetch ring: slot d holds row (t-1) for t = tb+d
    float uring[8];
    #pragma unroll
    for (int d = 0; d < 8; ++d) uring[d] = urow[d * KK + lane];

    float alpha = (lane == 1) ? 0.0f : NEGV;          // GO frame
    float alpha_prev = 0.0f;

    __syncthreads();

    for (int tb = 1; tb <= len; tb += 8) {
        #pragma unroll
        for (int k = 0; k < 8; ++k) {
            int t = tb + k;
            if (t > len) break;                       // wave-uniform
            const int p = (1 + k) & 1;                // tb always odd -> compile-time
            ((float*)&sA4[p][0])[lane] = alpha;       // broadcast alpha_{t-1}
            __builtin_amdgcn_wave_barrier();
            if (t >= 3) urow[(t - 2) * KK + lane] = alpha_prev;   // history row t-2
            float u_cur = uring[k];                   // unary row t-1 (loaded 8 iters ago)
            int rn = t + 7; if (rn > TT - 1) rn = TT - 1;
            uring[k] = urow[rn * KK + lane];          // prefetch row t+7

            float best0 = -1e30f, best1 = -1e30f;
            #pragma unroll
            for (int i4 = 0; i4 < 16; ++i4) {
                float4 a4 = sA4[p][i4];               // same-address broadcast read
                vf2 s01 = vf2{a4.x, a4.y} + Treg2[2 * i4];
                vf2 s23 = vf2{a4.z, a4.w} + Treg2[2 * i4 + 1];
                best0 = fmaxf(fmaxf(best0, s01.x), s01.y);   // v_max3
                best1 = fmaxf(fmaxf(best1, s23.x), s23.y);
            }
            alpha_prev = alpha;
            alpha = fmaxf(best0, best1) + u_cur;
        }
    }
    if (len >= 2) urow[(len - 1) * KK + lane] = alpha_prev;   // history row len-1

    // last = argmax_j alpha_final (first index on ties)
    float m = alpha;
    #pragma unroll
    for (int o = 32; o > 0; o >>= 1) m = fmaxf(m, __shfl_xor(m, o));
    unsigned long long msk = __ballot(alpha == m);
    int last = __ffsll(msk) - 1;

    for (int jj = len - 1 + lane; jj < TT; jj += 64) orow[jj] = last;

    __builtin_amdgcn_s_waitcnt(0);   // drain history stores before reading back

    // Backward: t = len..2, prev = argmax_i(alpha_{t-1}[i] + T[i][tag]).
    // depth-8 ring prefetch of alpha history rows (addresses are t-indexed,
    // only the tag->LDS-gather->reduce chain is serial).
    int tag = last;
    float aring[8];
    #pragma unroll
    for (int d = 0; d < 8; ++d) {
        int r = len - 1 - d;
        aring[d] = (r >= 1) ? urow[r * KK + lane] : 0.0f;
    }
    for (int tb = len; tb >= 2; tb -= 8) {
        #pragma unroll
        for (int k = 0; k < 8; ++k) {
            int t = tb - k;
            if (t < 2) break;                         // wave-uniform
            float a = aring[k];                       // alpha row t-1
            int r = t - 9;
            aring[k] = (r >= 1) ? urow[r * KK + lane] : 0.0f;   // for step t-8
            float v = a + sT[tag * KK + lane];        // bitwise same add as forward
            float mm = v;
            #pragma unroll
            for (int o = 32; o > 0; o >>= 1) mm = fmaxf(mm, __shfl_xor(mm, o));
            unsigned long long em = __ballot(v == mm);
            int prev = __ffsll(em) - 1;               // first i hitting the max
            if (lane == 0) orow[t - 2] = prev;
            tag = prev;
        }
    }
}

extern "C" void kernel_launch(void* const* d_in, const int* in_sizes, int n_in,
                              void* d_out, int out_size, void* d_ws, size_t ws_size,
                              hipStream_t stream)
{
    float*       unary   = (float*)d_in[0];          // clobbered; harness restores
    const int*   lengths = (const int*)d_in[1];
    const int*   inv     = (const int*)d_in[2];
    const float* A       = (const float*)d_in[3];
    int*         out     = (int*)d_out;

    float* trans  = (float*)d_ws;                    // 4096 floats
    float* transT = trans + KK * KK;                 // 4096 floats

    trans_kernel<<<KK, KK, 0, stream>>>(A, inv, trans, transT);
    viterbi_kernel<<<BB, KK, 0, stream>>>(unary, lengths, trans, transT, out);
}

// Round 5
// 505.008 us; speedup vs baseline: 1.1554x; 1.1554x over previous
//
#include <hip/hip_runtime.h>

#define NEGV -10000.0f
#define BB 1024
#define TT 512
#define KK 64

typedef float vf2 __attribute__((ext_vector_type(2)));

// ---------------------------------------------------------------------------
// K0: trans = log_softmax(A + inv_mask*NEG, axis=-1).
// ---------------------------------------------------------------------------
__global__ __launch_bounds__(64)
void trans_kernel(const float* __restrict__ A, const int* __restrict__ inv,
                  float* __restrict__ trans)
{
    const int i = blockIdx.x, j = threadIdx.x;
    float x = A[i * KK + j] + (inv[i * KK + j] ? NEGV : 0.0f);
    float m = x;
    #pragma unroll
    for (int o = 32; o > 0; o >>= 1) m = fmaxf(m, __shfl_xor(m, o));
    float e = expf(x - m);
    float s = e;
    #pragma unroll
    for (int o = 32; o > 0; o >>= 1) s += __shfl_xor(s, o);
    trans[i * KK + j] = (x - m) - logf(s);
}

// ---------------------------------------------------------------------------
// K1: fused Viterbi. One wave per sequence; lane = tag j.
// R5 redesign: forward computes backpointers directly (VALU was 9-13% busy
// in R1/R2 — the scan is nearly free in a latency-bound kernel) and stores
// them as BYTES in LDS (511x64 = 32 KB). Backward is a pure LDS pointer
// chase. No global history, no workspace >16KB, no restrict aliasing — the
// entire R2-R4 failure surface (alias vmcnt drains, ws faults) is removed.
// Pipeline order per step: read alpha_{t-1} -> m -> alpha_t -> ds_write
// next broadcast EARLY -> argmax scan + bp store in the LDS-latency shadow.
// ---------------------------------------------------------------------------
__global__ __launch_bounds__(64, 1)
void viterbi_kernel(const float* __restrict__ unary, const int* __restrict__ lengths,
                    const float* __restrict__ trans, int* __restrict__ out)
{
    const int lane = threadIdx.x;
    const int b = blockIdx.x;

    __shared__ unsigned char sbp[(TT - 1) * KK];   // bp rows t=2..512 -> [(t-2)*64+j]
    __shared__ float sAf[2 * KK];                  // alpha broadcast, double-buffered

    // Treg2[i] = {trans[2i][lane], trans[2i+1][lane]}  (coalesced loads)
    vf2 Treg2[KK / 2];
    #pragma unroll
    for (int i = 0; i < KK / 2; ++i) {
        Treg2[i].x = trans[(2 * i)     * KK + lane];
        Treg2[i].y = trans[(2 * i + 1) * KK + lane];
    }

    const int len = lengths[b];                    // 1..512, wave-uniform
    const float* ur = unary + (long)b * (TT * KK);
    int* orow = out + b * TT;

    float uring[8];                                // slot k: unary row t-1, t = tb+k
    #pragma unroll
    for (int d = 0; d < 8; ++d) uring[d] = ur[d * KK + lane];

    float alpha = (lane == 1) ? 0.0f : NEGV;       // GO frame
    sAf[lane] = alpha;                             // buffer 0 holds alpha_0
    __builtin_amdgcn_wave_barrier();

    for (int tb = 1; tb <= len; tb += 8) {         // tb odd -> parities compile-time
        #pragma unroll
        for (int k = 0; k < 8; ++k) {
            const int t = tb + k;                  // wave-uniform
            const int pin  = k & 1;                // alpha_{t-1} buffer
            const int pout = (k + 1) & 1;          // alpha_t buffer

            // scores sv[i] = alpha_{t-1}[i] + trans[i][lane]
            const float4* a4p = (const float4*)(sAf + pin * KK);
            float sv[KK];
            #pragma unroll
            for (int i4 = 0; i4 < 16; ++i4) {
                float4 a4 = a4p[i4];               // same-address broadcast reads
                vf2 t01 = vf2{a4.x, a4.y} + Treg2[2 * i4];
                vf2 t23 = vf2{a4.z, a4.w} + Treg2[2 * i4 + 1];
                sv[4 * i4 + 0] = t01.x; sv[4 * i4 + 1] = t01.y;
                sv[4 * i4 + 2] = t23.x; sv[4 * i4 + 3] = t23.y;
            }

            // m = max_i sv[i] — max3 tree, depth 4, ~32 instr
            float l0[22];
            #pragma unroll
            for (int i = 0; i < 21; ++i)
                l0[i] = fmaxf(fmaxf(sv[3 * i], sv[3 * i + 1]), sv[3 * i + 2]);
            l0[21] = sv[63];
            float l1[8];
            #pragma unroll
            for (int i = 0; i < 7; ++i)
                l1[i] = fmaxf(fmaxf(l0[3 * i], l0[3 * i + 1]), l0[3 * i + 2]);
            l1[7] = l0[21];
            float l2a = fmaxf(fmaxf(l1[0], l1[1]), l1[2]);
            float l2b = fmaxf(fmaxf(l1[3], l1[4]), l1[5]);
            float m   = fmaxf(fmaxf(l2a, l2b), fmaxf(l1[6], l1[7]));

            // alpha_t and EARLY broadcast kick (scan below hides the roundtrip)
            if (t <= len) alpha = m + uring[k];
            sAf[pout * KK + lane] = alpha;
            __builtin_amdgcn_wave_barrier();

            // refill prefetch ring (row t+7, clamped; off critical path)
            { int rn = t + 7; if (rn > TT - 1) rn = TT - 1;
              uring[k] = ur[rn * KK + lane]; }

            // first-index argmax (descending scan; m is bitwise one of sv,
            // ties -> smallest i == jnp.argmax). i in 0..63 are inline consts.
            int idx = 63;
            #pragma unroll
            for (int i = 62; i >= 0; --i) idx = (sv[i] == m) ? i : idx;
            if (t >= 2 && t <= len)
                sbp[(t - 2) * KK + lane] = (unsigned char)idx;
        }
    }

    // last = first-index argmax of final alpha (R1-validated shfl+ballot)
    float mm = alpha;
    #pragma unroll
    for (int o = 32; o > 0; o >>= 1) mm = fmaxf(mm, __shfl_xor(mm, o));
    unsigned long long msk = __ballot(alpha == mm);
    int last = __ffsll(msk) - 1;

    // positions >= len-1 carry `last`
    for (int jj = len - 1 + lane; jj < TT; jj += 64) orow[jj] = last;

    // backward: pure LDS chase. prev = bp_t[tag], out[t-2] = prev.
    int tag = last;
    for (int t = len; t >= 2; --t) {
        int prev = sbp[(t - 2) * KK + tag];        // wave-uniform broadcast read
        if (lane == 0) orow[t - 2] = prev;
        tag = prev;
    }
}

extern "C" void kernel_launch(void* const* d_in, const int* in_sizes, int n_in,
                              void* d_out, int out_size, void* d_ws, size_t ws_size,
                              hipStream_t stream)
{
    const float* unary   = (const float*)d_in[0];
    const int*   lengths = (const int*)d_in[1];
    const int*   inv     = (const int*)d_in[2];
    const float* A       = (const float*)d_in[3];
    int*         out     = (int*)d_out;

    float* trans = (float*)d_ws;                   // 4096 floats = 16 KB

    trans_kernel<<<KK, KK, 0, stream>>>(A, inv, trans);
    viterbi_kernel<<<BB, KK, 0, stream>>>(unary, lengths, trans, out);
}